// Round 16
// baseline (271.653 us; speedup 1.0000x reference)
//
#include <hip/hip_runtime.h>

#define NB   8
#define NPT  2048
#define NF   128
#define CR   64
#define EPSI 1e-5

// ============================ kNN (top-16, 2-D, exact f32+FMA emulation of np/jax) ============================
// PROVEN (rounds 6..15): ~96 us. FROZEN.
__global__ void __launch_bounds__(512) knn_kernel(const float* __restrict__ xyz,
                                                  int* __restrict__ idx16) {
  __shared__ float px[NPT], py[NPT], sxx[NPT];
  int b = blockIdx.x >> 8;                       // 2048 blocks: 256/batch, 8 queries/block
  const float* xb = xyz + b * 3 * NPT;
  for (int i = threadIdx.x; i < NPT; i += 512) {
    float x = xb[i], y = xb[NPT + i];
    px[i] = x; py[i] = y;
    sxx[i] = __fadd_rn(__fmul_rn(x, x), __fmul_rn(y, y));
  }
  __syncthreads();
  int lane = threadIdx.x & 63, wid = threadIdx.x >> 6;
  int q = ((blockIdx.x & 255) << 3) | wid;
  float qx = px[q], qy = py[q], qxx = sxx[q];
  float dc[32];
#pragma unroll 4
  for (int j = 0; j < 32; ++j) {
    int m = lane + (j << 6);
    float inner_s = __fmaf_rn(qy, py[m], __fmul_rn(qx, px[m]));
    dc[j] = __fadd_rn(__fsub_rn(qxx, __fmul_rn(2.0f, inner_s)), sxx[m]);
  }
  int keep = 0;
  for (int r = 0; r < 16; ++r) {
    float gd[8]; int gj[8];
#pragma unroll
    for (int g = 0; g < 8; ++g) {
      int base = g * 4;
      bool t01 = dc[base + 1] < dc[base];
      float d01 = t01 ? dc[base + 1] : dc[base];
      int   j01 = t01 ? base + 1 : base;
      bool t23 = dc[base + 3] < dc[base + 2];
      float d23 = t23 ? dc[base + 3] : dc[base + 2];
      int   j23 = t23 ? base + 3 : base + 2;
      bool t = d23 < d01;
      gd[g] = t ? d23 : d01;
      gj[g] = t ? j23 : j01;
    }
    float dmin = gd[0]; int jmin = gj[0];
#pragma unroll
    for (int g = 1; g < 8; ++g) {
      bool tt = gd[g] < dmin;
      dmin = tt ? gd[g] : dmin;
      jmin = tt ? gj[g] : jmin;
    }
    float hd = dmin;
    int   hm = lane + (jmin << 6);
#pragma unroll
    for (int off = 1; off < 64; off <<= 1) {
      float od = __shfl_xor(hd, off);
      int   om = __shfl_xor(hm, off);
      bool take = (od < hd) || (od == hd && om < hm);
      hd = take ? od : hd;
      hm = take ? om : hm;
    }
    if (lane == r) keep = hm;
    unsigned rf = (unsigned)__builtin_amdgcn_readfirstlane(hm);
    bool own = (rf & 63u) == (unsigned)lane;
    int jw = (int)(rf >> 6);
#pragma unroll
    for (int j = 0; j < 32; ++j)
      if (j == jw)
        dc[j] = own ? 1e38f : dc[j];
  }
  if (lane < 16) idx16[((b * NPT + q) << 4) + lane] = keep;
}

// ===================== conv1 vec4: 4 points/thread via float4; bit-identical per-point FMA chain =====================
template<int IC, int OC>
__global__ void __launch_bounds__(256) conv_stats_v4(const float* __restrict__ in,
                                                     const float* __restrict__ w,
                                                     const float* __restrict__ bias,
                                                     float* __restrict__ outp,
                                                     double* __restrict__ stats) {
  // grid = NB * (OC/8) * 2 ; block covers 1024 points x 8 channels
  int bz = blockIdx.x;
  int n0 = ((bz & 1) << 10) + threadIdx.x * 4;
  int o0 = ((bz >> 1) % (OC / 8)) * 8;
  int b  = bz / (2 * (OC / 8));
  const float4* inb4 = (const float4*)(in + b * IC * NPT + n0);
  float a[8][4];
#pragma unroll
  for (int t = 0; t < 8; ++t) {
    float bv = bias[o0 + t];
#pragma unroll
    for (int p = 0; p < 4; ++p) a[t][p] = bv;
  }
  const float* wb = w + o0 * IC;
#pragma unroll 2
  for (int f = 0; f < IC; ++f) {
    float4 v = inb4[f * (NPT / 4)];
#pragma unroll
    for (int t = 0; t < 8; ++t) {
      float wv = wb[t * IC + f];
      a[t][0] += wv * v.x; a[t][1] += wv * v.y; a[t][2] += wv * v.z; a[t][3] += wv * v.w;
    }
  }
  float* ob = outp + b * OC * NPT + n0;
#pragma unroll
  for (int t = 0; t < 8; ++t)
    *(float4*)(ob + (o0 + t) * NPT) = make_float4(a[t][0], a[t][1], a[t][2], a[t][3]);
  __shared__ double red[4][8][2];
  int lane = threadIdx.x & 63, wid = threadIdx.x >> 6;
#pragma unroll
  for (int j = 0; j < 8; ++j) {
    double s1 = (double)a[j][0] + (double)a[j][1] + (double)a[j][2] + (double)a[j][3];
    double s2 = (double)a[j][0]*(double)a[j][0] + (double)a[j][1]*(double)a[j][1]
              + (double)a[j][2]*(double)a[j][2] + (double)a[j][3]*(double)a[j][3];
#pragma unroll
    for (int off = 32; off; off >>= 1) { s1 += __shfl_down(s1, off); s2 += __shfl_down(s2, off); }
    if (lane == 0) { red[wid][j][0] = s1; red[wid][j][1] = s2; }
  }
  __syncthreads();
  if (threadIdx.x < 8) {
    int j = threadIdx.x;
    double S1 = red[0][j][0] + red[1][j][0] + red[2][j][0] + red[3][j][0];
    double S2 = red[0][j][1] + red[1][j][1] + red[2][j][1] + red[3][j][1];
    atomicAdd(&stats[o0 + j], S1);
    atomicAdd(&stats[OC + o0 + j], S2);
  }
}

// ===================== BN finalize + ReLU, float4 (round-7 proven; bn3) =====================
template<int C>
__global__ void __launch_bounds__(256) bn_apply(const float* __restrict__ pre,
                                                const float* __restrict__ addsrc,
                                                float* __restrict__ outp,
                                                const double* __restrict__ stats,
                                                const float* __restrict__ gam,
                                                const float* __restrict__ bet,
                                                double inv_cnt) {
  __shared__ float sc[C], sh[C];
  for (int c = threadIdx.x; c < C; c += 256) {
    double mu    = stats[c] * inv_cnt;
    double var   = stats[C + c] * inv_cnt - mu * mu;
    double scale = (double)gam[c] / sqrt(var + EPSI);
    sc[c] = (float)scale;
    sh[c] = (float)((double)bet[c] - mu * scale);
  }
  __syncthreads();
  const float4* pre4 = (const float4*)pre;
  const float4* add4 = (const float4*)addsrc;
  float4* out4 = (float4*)outp;
  int total4 = NB * C * (NPT / 4);
  for (int i = blockIdx.x * 256 + threadIdx.x; i < total4; i += gridDim.x * 256) {
    int c = (i >> 9) & (C - 1);
    float s = sc[c], h = sh[c];
    float4 v = pre4[i];
    v.x = fmaxf(v.x * s + h, 0.f);
    v.y = fmaxf(v.y * s + h, 0.f);
    v.z = fmaxf(v.z * s + h, 0.f);
    v.w = fmaxf(v.w * s + h, 0.f);
    if (addsrc) {
      float4 a = add4[i];
      v.x += a.x; v.y += a.y; v.z += a.z; v.w += a.w;
    }
    out4[i] = v;
  }
}

// ===================== zconv vec4: z = Wf·relu(bn1(x1pre)) + bf -> zT[n][o]; 4 points/thread =====================
__global__ void __launch_bounds__(256) zconv_kernel(const float* __restrict__ x1pre,
                                                    const double* __restrict__ st0,
                                                    const float* __restrict__ g1,
                                                    const float* __restrict__ be1,
                                                    const float* __restrict__ wf,
                                                    const float* __restrict__ bfp,
                                                    float* __restrict__ zT) {
  __shared__ float sc[64], sh[64];
  if (threadIdx.x < 64) {
    int c = threadIdx.x;
    double mu  = st0[c] / 16384.0;
    double var = st0[64 + c] / 16384.0 - mu * mu;
    double s   = (double)g1[c] / sqrt(var + EPSI);
    sc[c] = (float)s;
    sh[c] = (float)((double)be1[c] - mu * s);
  }
  __syncthreads();
  int bz = blockIdx.x;                           // 128 blocks: [b(8)][og(8)][ng(2)]
  int n0 = ((bz & 1) << 10) + threadIdx.x * 4;
  int o0 = ((bz >> 1) % 8) * 8;
  int b  = bz / 16;
  const float4* inb4 = (const float4*)(x1pre + b * CR * NPT + n0);
  float a[8][4];
#pragma unroll
  for (int t = 0; t < 8; ++t) {
    float bv = bfp[o0 + t];
#pragma unroll
    for (int p = 0; p < 4; ++p) a[t][p] = bv;
  }
  const float* wb = wf + o0 * CR;
#pragma unroll 2
  for (int f = 0; f < CR; ++f) {
    float4 r = inb4[f * (NPT / 4)];
    float4 v;
    v.x = fmaxf(fmaf(r.x, sc[f], sh[f]), 0.f);
    v.y = fmaxf(fmaf(r.y, sc[f], sh[f]), 0.f);
    v.z = fmaxf(fmaf(r.z, sc[f], sh[f]), 0.f);
    v.w = fmaxf(fmaf(r.w, sc[f], sh[f]), 0.f);
#pragma unroll
    for (int t = 0; t < 8; ++t) {
      float wv = wb[t * CR + f];
      a[t][0] += wv * v.x; a[t][1] += wv * v.y; a[t][2] += wv * v.z; a[t][3] += wv * v.w;
    }
  }
#pragma unroll
  for (int p = 0; p < 4; ++p) {
    float* zp = zT + ((b * NPT + n0 + p) << 6) + o0;
    *(float4*)(zp)     = make_float4(a[0][p], a[1][p], a[2][p], a[3][p]);
    *(float4*)(zp + 4) = make_float4(a[4][p], a[5][p], a[6][p], a[7][p]);
  }
}

// ===================== gathermax (r13-proven): h[o,n,k] = zT[src(n,k)][o]; max over k + f64 stats =====================
__global__ void __launch_bounds__(256) gathermax_kernel(const float* __restrict__ zT,
                                                        const int* __restrict__ idx16,
                                                        float* __restrict__ hmax,
                                                        double* __restrict__ stats) {
  __shared__ double dred[4][64][2];
  int lane = threadIdx.x & 63, wid = threadIdx.x >> 6;
  int wave = blockIdx.x * 4 + wid;               // 1024 blocks, 4 pts/wave
  double s1 = 0.0, s2 = 0.0;
  for (int p = 0; p < 4; ++p) {
    int pt = wave * 4 + p;
    int b = pt >> 11, n = pt & 2047;
    const float* zb = zT + ((b * NPT) << 6);
    float vals[8];
#pragma unroll
    for (int k = 0; k < 8; ++k) {
      int j = k * NPT + n;                       // torch-view scramble: idx[(j>>3), j&7]
      int src = idx16[((b * NPT + (j >> 3)) << 4) | (j & 7)];
      vals[k] = zb[(src << 6) + lane];           // coalesced: 64 lanes read 256B
    }
    float hm = vals[0];
#pragma unroll
    for (int k = 0; k < 8; ++k) {
      hm = fmaxf(hm, vals[k]);
      s1 += (double)vals[k];
      s2 += (double)vals[k] * (double)vals[k];
    }
    hmax[(b * CR + lane) * NPT + n] = hm;        // max commutes with BN+ReLU (gamma>0)
  }
  dred[wid][lane][0] = s1; dred[wid][lane][1] = s2;
  __syncthreads();
  if (threadIdx.x < 64) {
    double S1 = dred[0][threadIdx.x][0] + dred[1][threadIdx.x][0] + dred[2][threadIdx.x][0] + dred[3][threadIdx.x][0];
    double S2 = dred[0][threadIdx.x][1] + dred[1][threadIdx.x][1] + dred[2][threadIdx.x][1] + dred[3][threadIdx.x][1];
    atomicAdd(&stats[threadIdx.x], S1);
    atomicAdd(&stats[64 + threadIdx.x], S2);
  }
}

// ===================== lap_fused (rounds 8/11..15 VALIDATED): BN_g inline + mean-gather + 64x64 FC =====================
__global__ void __launch_bounds__(256) lap_fused(const float* __restrict__ hpre,
                                                 const int* __restrict__ idx16,
                                                 const float* __restrict__ wl,
                                                 const float* __restrict__ blp,
                                                 float* __restrict__ tpre,
                                                 double* __restrict__ stats,
                                                 const double* __restrict__ stg,
                                                 const float* __restrict__ gg,
                                                 const float* __restrict__ bg) {
  __shared__ float wlT[64 * 65];
  __shared__ double dred[4][64][2];
  __shared__ float vstage[4][64];
  __shared__ float scg[64], shg[64];
  for (int i = threadIdx.x; i < 64 * 64; i += 256) {
    int o = i >> 6, f = i & 63;
    wlT[f * 65 + o] = wl[i];
  }
  if (threadIdx.x < 64) {
    int c = threadIdx.x;
    double mu  = stg[c] / 131072.0;
    double var = stg[64 + c] / 131072.0 - mu * mu;
    double s   = (double)gg[c] / sqrt(var + EPSI);
    scg[c] = (float)s;
    shg[c] = (float)((double)bg[c] - mu * s);
  }
  __syncthreads();
  int lane = threadIdx.x & 63, wid = threadIdx.x >> 6;
  int g = lane >> 4, cc = lane & 15;
  float blv = blp[lane];
  double s1 = 0.0, s2 = 0.0;
  for (int p = 0; p < 4; ++p) {
    int pt = (blockIdx.x * 4 + wid) * 4 + p;
    int b = pt >> 11, n = pt & 2047;
    int ch = n >> 5;                             // gathered CHANNEL is n>>5 (torch-view scramble)
    int r0 = (n & 31) << 6;
    const float* xrow = hpre + (b * CR + ch) * NPT;
    const int* ib = idx16 + ((b * NPT + r0) << 4);
    float sgc = scg[ch], shc = shg[ch];
    float msum = 0.f;
#pragma unroll
    for (int kk = 0; kk < 16; ++kk) {
      int sidx = ib[(((kk << 2) + g) << 4) | cc];
      msum += fmaxf(fmaf(xrow[sidx], sgc, shc), 0.f);    // BN_g inline
    }
    float mval = msum * 0.0625f;
    float xraw = hpre[(b * CR + lane) * NPT + n];
    float xv = fmaxf(fmaf(xraw, scg[lane], shg[lane]), 0.f);
    vstage[wid][lane] = xv - mval;
    float acc = blv;
    for (int f = 0; f < 64; ++f)
      acc += wlT[f * 65 + lane] * vstage[wid][f];
    tpre[(b * CR + lane) * NPT + n] = acc;
    s1 += (double)acc;
    s2 += (double)acc * (double)acc;
  }
  dred[wid][lane][0] = s1; dred[wid][lane][1] = s2;
  __syncthreads();
  if (threadIdx.x < 64) {
    double S1 = dred[0][threadIdx.x][0] + dred[1][threadIdx.x][0] + dred[2][threadIdx.x][0] + dred[3][threadIdx.x][0];
    double S2 = dred[0][threadIdx.x][1] + dred[1][threadIdx.x][1] + dred[2][threadIdx.x][1] + dred[3][threadIdx.x][1];
    atomicAdd(&stats[threadIdx.x], S1);
    atomicAdd(&stats[64 + threadIdx.x], S2);
  }
}

// ===================== conv2_fused vec4: x3 = relu(bn_g(h)) + relu(bn_l(t)) inline; 4 points/thread =====================
__global__ void __launch_bounds__(256) conv2_fused(const float* __restrict__ hpre,
                                                   const float* __restrict__ tpre,
                                                   const double* __restrict__ stg,
                                                   const float* __restrict__ gg,
                                                   const float* __restrict__ bg,
                                                   const double* __restrict__ stl,
                                                   const float* __restrict__ gl,
                                                   const float* __restrict__ bel,
                                                   const float* __restrict__ w,
                                                   const float* __restrict__ bias,
                                                   float* __restrict__ outp,
                                                   double* __restrict__ stats) {
  __shared__ float scg[64], shg[64], scl[64], shl[64];
  __shared__ double red[4][8][2];
  if (threadIdx.x < 64) {
    int c = threadIdx.x;
    double mu  = stg[c] / 131072.0;
    double var = stg[64 + c] / 131072.0 - mu * mu;
    double s   = (double)gg[c] / sqrt(var + EPSI);
    scg[c] = (float)s; shg[c] = (float)((double)bg[c] - mu * s);
    double mu2  = stl[c] / 16384.0;
    double var2 = stl[64 + c] / 16384.0 - mu2 * mu2;
    double s2   = (double)gl[c] / sqrt(var2 + EPSI);
    scl[c] = (float)s2; shl[c] = (float)((double)bel[c] - mu2 * s2);
  }
  __syncthreads();
  int bz = blockIdx.x;                           // 256 blocks: [b(8)][og(16)][ng(2)]
  int n0 = ((bz & 1) << 10) + threadIdx.x * 4;
  int o0 = ((bz >> 1) % 16) * 8;
  int b  = bz / 32;
  const float4* hb4 = (const float4*)(hpre + b * CR * NPT + n0);
  const float4* tb4 = (const float4*)(tpre + b * CR * NPT + n0);
  float a[8][4];
#pragma unroll
  for (int t = 0; t < 8; ++t) {
    float bv = bias[o0 + t];
#pragma unroll
    for (int p = 0; p < 4; ++p) a[t][p] = bv;
  }
  const float* wb = w + o0 * CR;
#pragma unroll 2
  for (int f = 0; f < CR; ++f) {
    float4 hv = hb4[f * (NPT / 4)];
    float4 tv = tb4[f * (NPT / 4)];
    float sg = scg[f], hg = shg[f], sl = scl[f], hl = shl[f];
    float4 v;
    v.x = fmaxf(fmaf(hv.x, sg, hg), 0.f) + fmaxf(fmaf(tv.x, sl, hl), 0.f);
    v.y = fmaxf(fmaf(hv.y, sg, hg), 0.f) + fmaxf(fmaf(tv.y, sl, hl), 0.f);
    v.z = fmaxf(fmaf(hv.z, sg, hg), 0.f) + fmaxf(fmaf(tv.z, sl, hl), 0.f);
    v.w = fmaxf(fmaf(hv.w, sg, hg), 0.f) + fmaxf(fmaf(tv.w, sl, hl), 0.f);
#pragma unroll
    for (int t = 0; t < 8; ++t) {
      float wv = wb[t * CR + f];
      a[t][0] += wv * v.x; a[t][1] += wv * v.y; a[t][2] += wv * v.z; a[t][3] += wv * v.w;
    }
  }
  float* ob = outp + b * NF * NPT + n0;
#pragma unroll
  for (int t = 0; t < 8; ++t)
    *(float4*)(ob + (o0 + t) * NPT) = make_float4(a[t][0], a[t][1], a[t][2], a[t][3]);
  int lane = threadIdx.x & 63, wid = threadIdx.x >> 6;
#pragma unroll
  for (int j = 0; j < 8; ++j) {
    double s1 = (double)a[j][0] + (double)a[j][1] + (double)a[j][2] + (double)a[j][3];
    double s2 = (double)a[j][0]*(double)a[j][0] + (double)a[j][1]*(double)a[j][1]
              + (double)a[j][2]*(double)a[j][2] + (double)a[j][3]*(double)a[j][3];
#pragma unroll
    for (int off = 32; off; off >>= 1) { s1 += __shfl_down(s1, off); s2 += __shfl_down(s2, off); }
    if (lane == 0) { red[wid][j][0] = s1; red[wid][j][1] = s2; }
  }
  __syncthreads();
  if (threadIdx.x < 8) {
    int j = threadIdx.x;
    double S1 = red[0][j][0] + red[1][j][0] + red[2][j][0] + red[3][j][0];
    double S2 = red[0][j][1] + red[1][j][1] + red[2][j][1] + red[3][j][1];
    atomicAdd(&stats[o0 + j], S1);
    atomicAdd(&stats[NF + o0 + j], S2);
  }
}

// ===================== conv3_fused vec4: y2 = relu(bn2(y2pre)) + feat inline; 4 points/thread =====================
__global__ void __launch_bounds__(256) conv3_fused(const float* __restrict__ y2pre,
                                                   const float* __restrict__ feat,
                                                   const double* __restrict__ st2,
                                                   const float* __restrict__ g2,
                                                   const float* __restrict__ be2,
                                                   const float* __restrict__ w,
                                                   const float* __restrict__ bias,
                                                   float* __restrict__ outp,
                                                   double* __restrict__ stats) {
  __shared__ float sc[128], sh[128];
  __shared__ double red[4][8][2];
  for (int c = threadIdx.x; c < 128; c += 256) {
    double mu  = st2[c] / 16384.0;
    double var = st2[128 + c] / 16384.0 - mu * mu;
    double s   = (double)g2[c] / sqrt(var + EPSI);
    sc[c] = (float)s;
    sh[c] = (float)((double)be2[c] - mu * s);
  }
  __syncthreads();
  int bz = blockIdx.x;                           // 512 blocks: [b(8)][og(32)][ng(2)]
  int n0 = ((bz & 1) << 10) + threadIdx.x * 4;
  int o0 = ((bz >> 1) % 32) * 8;
  int b  = bz / 64;
  const float4* yb4 = (const float4*)(y2pre + b * NF * NPT + n0);
  const float4* fb4 = (const float4*)(feat  + b * NF * NPT + n0);
  float a[8][4];
#pragma unroll
  for (int t = 0; t < 8; ++t) {
    float bv = bias[o0 + t];
#pragma unroll
    for (int p = 0; p < 4; ++p) a[t][p] = bv;
  }
  const float* wb = w + o0 * NF;
#pragma unroll 2
  for (int f = 0; f < NF; ++f) {
    float4 yv = yb4[f * (NPT / 4)];
    float4 fv = fb4[f * (NPT / 4)];
    float s = sc[f], h = sh[f];
    float4 v;
    v.x = fmaxf(fmaf(yv.x, s, h), 0.f) + fv.x;
    v.y = fmaxf(fmaf(yv.y, s, h), 0.f) + fv.y;
    v.z = fmaxf(fmaf(yv.z, s, h), 0.f) + fv.z;
    v.w = fmaxf(fmaf(yv.w, s, h), 0.f) + fv.w;
#pragma unroll
    for (int t = 0; t < 8; ++t) {
      float wv = wb[t * NF + f];
      a[t][0] += wv * v.x; a[t][1] += wv * v.y; a[t][2] += wv * v.z; a[t][3] += wv * v.w;
    }
  }
  float* ob = outp + b * 2 * NF * NPT + n0;
#pragma unroll
  for (int t = 0; t < 8; ++t)
    *(float4*)(ob + (o0 + t) * NPT) = make_float4(a[t][0], a[t][1], a[t][2], a[t][3]);
  int lane = threadIdx.x & 63, wid = threadIdx.x >> 6;
#pragma unroll
  for (int j = 0; j < 8; ++j) {
    double s1 = (double)a[j][0] + (double)a[j][1] + (double)a[j][2] + (double)a[j][3];
    double s2 = (double)a[j][0]*(double)a[j][0] + (double)a[j][1]*(double)a[j][1]
              + (double)a[j][2]*(double)a[j][2] + (double)a[j][3]*(double)a[j][3];
#pragma unroll
    for (int off = 32; off; off >>= 1) { s1 += __shfl_down(s1, off); s2 += __shfl_down(s2, off); }
    if (lane == 0) { red[wid][j][0] = s1; red[wid][j][1] = s2; }
  }
  __syncthreads();
  if (threadIdx.x < 8) {
    int j = threadIdx.x;
    double S1 = red[0][j][0] + red[1][j][0] + red[2][j][0] + red[3][j][0];
    double S2 = red[0][j][1] + red[1][j][1] + red[2][j][1] + red[3][j][1];
    atomicAdd(&stats[o0 + j], S1);
    atomicAdd(&stats[256 + o0 + j], S2);
  }
}

// ============================ launch (9 nodes) ============================
extern "C" void kernel_launch(void* const* d_in, const int* in_sizes, int n_in,
                              void* d_out, int out_size, void* d_ws, size_t ws_size,
                              hipStream_t stream) {
  const float* xyz  = (const float*)d_in[0];
  const float* feat = (const float*)d_in[1];
  const float* w1   = (const float*)d_in[2];
  const float* b1   = (const float*)d_in[3];
  const float* g1   = (const float*)d_in[4];
  const float* be1  = (const float*)d_in[5];
  const float* wf   = (const float*)d_in[6];
  const float* bf   = (const float*)d_in[7];
  const float* gg   = (const float*)d_in[8];
  const float* bg   = (const float*)d_in[9];
  const float* wl   = (const float*)d_in[10];
  const float* bl   = (const float*)d_in[11];
  const float* gl   = (const float*)d_in[12];
  const float* bel  = (const float*)d_in[13];
  const float* w2   = (const float*)d_in[14];
  const float* b2   = (const float*)d_in[15];
  const float* g2   = (const float*)d_in[16];
  const float* be2  = (const float*)d_in[17];
  const float* w3   = (const float*)d_in[18];
  const float* b3   = (const float*)d_in[19];
  const float* g3   = (const float*)d_in[20];
  const float* be3  = (const float*)d_in[21];
  float* out = (float*)d_out;

  // d_out scratch (all dead before conv3 writes out):
  float* x1pre = out;                      // 4MB  (pre-BN conv1 out; consumed by zconv)
  float* tpre  = out + 1048576;            // 4MB
  int*  idx16  = (int*)(out + 2097152);    // 1MB
  float* zT    = out + 2359296;            // 4MB  zT[b][n][64]
  // ws: hpre, y2pre, stats (12MB + 9KB footprint, as all passing rounds)
  float*  hpre  = (float*)d_ws;            // 4MB
  float*  y2pre = hpre + 1048576;          // 8MB (pre-BN conv2 out; bn2 applied inside conv3)
  double* stats = (double*)((char*)d_ws + (12u << 20));
  double* st0 = stats;        // 128
  double* stg = stats + 128;  // 128
  double* stl = stats + 256;  // 128
  double* st2 = stats + 384;  // 256
  double* st3 = stats + 640;  // 512

  hipMemsetAsync(stats, 0, 1152 * sizeof(double), stream);

  // 1: kNN (512-thread blocks, 8 queries/block)
  knn_kernel<<<2048, 512, 0, stream>>>(xyz, idx16);
  // 2: conv1 vec4 -> x1pre + st0
  conv_stats_v4<128, 64><<<128, 256, 0, stream>>>(feat, w1, b1, x1pre, st0);
  // 3: zconv vec4 (bn1 inline) -> zT
  zconv_kernel<<<128, 256, 0, stream>>>(x1pre, st0, g1, be1, wf, bf, zT);
  // 4: gathermax -> hpre (pre-BN max) + stg
  gathermax_kernel<<<1024, 256, 0, stream>>>(zT, idx16, hpre, stg);
  // 5: lap (BN_g inline) -> tpre + stl
  lap_fused<<<1024, 256, 0, stream>>>(hpre, idx16, wl, bl, tpre, stl, stg, gg, bg);
  // 6: conv2 vec4 (x3 inline) -> y2pre + st2
  conv2_fused<<<256, 256, 0, stream>>>(hpre, tpre, stg, gg, bg, stl, gl, bel, w2, b2, y2pre, st2);
  // 7: conv3 vec4 (bn2 + feat residual inline) -> out + st3
  conv3_fused<<<512, 256, 0, stream>>>(y2pre, feat, st2, g2, be2, w3, b3, out, st3);
  // 8: bn3 -> out in place
  bn_apply<256><<<1024, 256, 0, stream>>>(out, nullptr, out, st3, g3, be3, 1.0 / 16384.0);
}

// Round 17
// 252.904 us; speedup vs baseline: 1.0741x; 1.0741x over previous
//
#include <hip/hip_runtime.h>

#define NB   8
#define NPT  2048
#define NF   128
#define CR   64
#define EPSI 1e-5

// ============================ kNN (top-16, 2-D, exact f32+FMA emulation of np/jax) ============================
// PROVEN (rounds 6..15): ~96 us, VALU/chain-bound. FROZEN (r15 optimum).
__global__ void __launch_bounds__(512) knn_kernel(const float* __restrict__ xyz,
                                                  int* __restrict__ idx16) {
  __shared__ float px[NPT], py[NPT], sxx[NPT];
  int b = blockIdx.x >> 8;                       // 2048 blocks: 256/batch, 8 queries/block
  const float* xb = xyz + b * 3 * NPT;
  for (int i = threadIdx.x; i < NPT; i += 512) {
    float x = xb[i], y = xb[NPT + i];
    px[i] = x; py[i] = y;
    sxx[i] = __fadd_rn(__fmul_rn(x, x), __fmul_rn(y, y));
  }
  __syncthreads();
  int lane = threadIdx.x & 63, wid = threadIdx.x >> 6;
  int q = ((blockIdx.x & 255) << 3) | wid;
  float qx = px[q], qy = py[q], qxx = sxx[q];
  float dc[32];
#pragma unroll 4
  for (int j = 0; j < 32; ++j) {
    int m = lane + (j << 6);
    float inner_s = __fmaf_rn(qy, py[m], __fmul_rn(qx, px[m]));
    dc[j] = __fadd_rn(__fsub_rn(qxx, __fmul_rn(2.0f, inner_s)), sxx[m]);
  }
  int keep = 0;
  for (int r = 0; r < 16; ++r) {
    float gd[8]; int gj[8];
#pragma unroll
    for (int g = 0; g < 8; ++g) {
      int base = g * 4;
      bool t01 = dc[base + 1] < dc[base];
      float d01 = t01 ? dc[base + 1] : dc[base];
      int   j01 = t01 ? base + 1 : base;
      bool t23 = dc[base + 3] < dc[base + 2];
      float d23 = t23 ? dc[base + 3] : dc[base + 2];
      int   j23 = t23 ? base + 3 : base + 2;
      bool t = d23 < d01;
      gd[g] = t ? d23 : d01;
      gj[g] = t ? j23 : j01;
    }
    float dmin = gd[0]; int jmin = gj[0];
#pragma unroll
    for (int g = 1; g < 8; ++g) {
      bool tt = gd[g] < dmin;
      dmin = tt ? gd[g] : dmin;
      jmin = tt ? gj[g] : jmin;
    }
    float hd = dmin;
    int   hm = lane + (jmin << 6);
#pragma unroll
    for (int off = 1; off < 64; off <<= 1) {
      float od = __shfl_xor(hd, off);
      int   om = __shfl_xor(hm, off);
      bool take = (od < hd) || (od == hd && om < hm);
      hd = take ? od : hd;
      hm = take ? om : hm;
    }
    if (lane == r) keep = hm;
    unsigned rf = (unsigned)__builtin_amdgcn_readfirstlane(hm);
    bool own = (rf & 63u) == (unsigned)lane;
    int jw = (int)(rf >> 6);
#pragma unroll
    for (int j = 0; j < 32; ++j)
      if (j == jw)
        dc[j] = own ? 1e38f : dc[j];
  }
  if (lane < 16) idx16[((b * NPT + q) << 4) + lane] = keep;
}

// ===================== generic conv + atomic stats, 8 ch/block (round-7/11 proven; conv1) =====================
template<int IC, int OC>
__global__ void __launch_bounds__(256) conv_stats(const float* __restrict__ in,
                                                  const float* __restrict__ w,
                                                  const float* __restrict__ bias,
                                                  float* __restrict__ outp,
                                                  double* __restrict__ stats) {
  int bz = blockIdx.x;
  int n  = ((bz & 7) << 8) | threadIdx.x;
  int o0 = ((bz >> 3) % (OC / 8)) * 8;
  int b  = bz / (8 * (OC / 8));
  const float* inb = in + b * IC * NPT + n;
  float a[8];
#pragma unroll
  for (int t = 0; t < 8; ++t) a[t] = bias[o0 + t];
  const float* wb = w + o0 * IC;
#pragma unroll 4
  for (int f = 0; f < IC; ++f) {
    float v = inb[f * NPT];
#pragma unroll
    for (int t = 0; t < 8; ++t) a[t] += wb[t * IC + f] * v;
  }
  float* ob = outp + b * OC * NPT + n;
#pragma unroll
  for (int t = 0; t < 8; ++t) ob[(o0 + t) * NPT] = a[t];
  __shared__ double red[4][8][2];
  int lane = threadIdx.x & 63, wid = threadIdx.x >> 6;
#pragma unroll
  for (int j = 0; j < 8; ++j) {
    double s1 = (double)a[j];
    double s2 = (double)a[j] * (double)a[j];
#pragma unroll
    for (int off = 32; off; off >>= 1) { s1 += __shfl_down(s1, off); s2 += __shfl_down(s2, off); }
    if (lane == 0) { red[wid][j][0] = s1; red[wid][j][1] = s2; }
  }
  __syncthreads();
  if (threadIdx.x < 8) {
    int j = threadIdx.x;
    double S1 = red[0][j][0] + red[1][j][0] + red[2][j][0] + red[3][j][0];
    double S2 = red[0][j][1] + red[1][j][1] + red[2][j][1] + red[3][j][1];
    atomicAdd(&stats[o0 + j], S1);
    atomicAdd(&stats[OC + o0 + j], S2);
  }
}

// ===================== BN finalize + ReLU, float4 (round-7 proven; bn3) =====================
template<int C>
__global__ void __launch_bounds__(256) bn_apply(const float* __restrict__ pre,
                                                const float* __restrict__ addsrc,
                                                float* __restrict__ outp,
                                                const double* __restrict__ stats,
                                                const float* __restrict__ gam,
                                                const float* __restrict__ bet,
                                                double inv_cnt) {
  __shared__ float sc[C], sh[C];
  for (int c = threadIdx.x; c < C; c += 256) {
    double mu    = stats[c] * inv_cnt;
    double var   = stats[C + c] * inv_cnt - mu * mu;
    double scale = (double)gam[c] / sqrt(var + EPSI);
    sc[c] = (float)scale;
    sh[c] = (float)((double)bet[c] - mu * scale);
  }
  __syncthreads();
  const float4* pre4 = (const float4*)pre;
  const float4* add4 = (const float4*)addsrc;
  float4* out4 = (float4*)outp;
  int total4 = NB * C * (NPT / 4);
  for (int i = blockIdx.x * 256 + threadIdx.x; i < total4; i += gridDim.x * 256) {
    int c = (i >> 9) & (C - 1);
    float s = sc[c], h = sh[c];
    float4 v = pre4[i];
    v.x = fmaxf(v.x * s + h, 0.f);
    v.y = fmaxf(v.y * s + h, 0.f);
    v.z = fmaxf(v.z * s + h, 0.f);
    v.w = fmaxf(v.w * s + h, 0.f);
    if (addsrc) {
      float4 a = add4[i];
      v.x += a.x; v.y += a.y; v.z += a.z; v.w += a.w;
    }
    out4[i] = v;
  }
}

// ===================== zconv (r13-proven): z = Wf·relu(bn1(x1pre)) + bf, stored zT[n][o] =====================
__global__ void __launch_bounds__(256) zconv_kernel(const float* __restrict__ x1pre,
                                                    const double* __restrict__ st0,
                                                    const float* __restrict__ g1,
                                                    const float* __restrict__ be1,
                                                    const float* __restrict__ wf,
                                                    const float* __restrict__ bfp,
                                                    float* __restrict__ zT) {
  __shared__ float sc[64], sh[64];
  if (threadIdx.x < 64) {
    int c = threadIdx.x;
    double mu  = st0[c] / 16384.0;
    double var = st0[64 + c] / 16384.0 - mu * mu;
    double s   = (double)g1[c] / sqrt(var + EPSI);
    sc[c] = (float)s;
    sh[c] = (float)((double)be1[c] - mu * s);
  }
  __syncthreads();
  int bz = blockIdx.x;                           // 512 blocks: [b(8)][og(8)][ng(8)]
  int n  = ((bz & 7) << 8) | threadIdx.x;
  int o0 = ((bz >> 3) % 8) * 8;
  int b  = bz / 64;
  const float* inb = x1pre + b * CR * NPT + n;
  float a[8];
#pragma unroll
  for (int t = 0; t < 8; ++t) a[t] = bfp[o0 + t];
  const float* wb = wf + o0 * CR;
#pragma unroll 4
  for (int f = 0; f < CR; ++f) {
    float v = fmaxf(fmaf(inb[f * NPT], sc[f], sh[f]), 0.f);   // bn1 + relu inline
#pragma unroll
    for (int t = 0; t < 8; ++t) a[t] += wb[t * CR + f] * v;
  }
  float* zp = zT + ((b * NPT + n) << 6) + o0;    // zT[b][n][o]
  *(float4*)(zp)     = make_float4(a[0], a[1], a[2], a[3]);
  *(float4*)(zp + 4) = make_float4(a[4], a[5], a[6], a[7]);
}

// ===================== gathermax (r13-proven): h[o,n,k] = zT[src(n,k)][o]; max over k + f64 stats =====================
__global__ void __launch_bounds__(256) gathermax_kernel(const float* __restrict__ zT,
                                                        const int* __restrict__ idx16,
                                                        float* __restrict__ hmax,
                                                        double* __restrict__ stats) {
  __shared__ double dred[4][64][2];
  int lane = threadIdx.x & 63, wid = threadIdx.x >> 6;
  int wave = blockIdx.x * 4 + wid;               // 1024 blocks, 4 pts/wave
  double s1 = 0.0, s2 = 0.0;
  for (int p = 0; p < 4; ++p) {
    int pt = wave * 4 + p;
    int b = pt >> 11, n = pt & 2047;
    const float* zb = zT + ((b * NPT) << 6);
    float vals[8];
#pragma unroll
    for (int k = 0; k < 8; ++k) {
      int j = k * NPT + n;                       // torch-view scramble: idx[(j>>3), j&7]
      int src = idx16[((b * NPT + (j >> 3)) << 4) | (j & 7)];
      vals[k] = zb[(src << 6) + lane];           // coalesced: 64 lanes read 256B
    }
    float hm = vals[0];
#pragma unroll
    for (int k = 0; k < 8; ++k) {
      hm = fmaxf(hm, vals[k]);
      s1 += (double)vals[k];
      s2 += (double)vals[k] * (double)vals[k];
    }
    hmax[(b * CR + lane) * NPT + n] = hm;        // max commutes with BN+ReLU (gamma>0)
  }
  dred[wid][lane][0] = s1; dred[wid][lane][1] = s2;
  __syncthreads();
  if (threadIdx.x < 64) {
    double S1 = dred[0][threadIdx.x][0] + dred[1][threadIdx.x][0] + dred[2][threadIdx.x][0] + dred[3][threadIdx.x][0];
    double S2 = dred[0][threadIdx.x][1] + dred[1][threadIdx.x][1] + dred[2][threadIdx.x][1] + dred[3][threadIdx.x][1];
    atomicAdd(&stats[threadIdx.x], S1);
    atomicAdd(&stats[64 + threadIdx.x], S2);
  }
}

// ===================== lap_fused (rounds 8/11..15 VALIDATED): BN_g inline + mean-gather + 64x64 FC =====================
__global__ void __launch_bounds__(256) lap_fused(const float* __restrict__ hpre,
                                                 const int* __restrict__ idx16,
                                                 const float* __restrict__ wl,
                                                 const float* __restrict__ blp,
                                                 float* __restrict__ tpre,
                                                 double* __restrict__ stats,
                                                 const double* __restrict__ stg,
                                                 const float* __restrict__ gg,
                                                 const float* __restrict__ bg) {
  __shared__ float wlT[64 * 65];
  __shared__ double dred[4][64][2];
  __shared__ float vstage[4][64];
  __shared__ float scg[64], shg[64];
  for (int i = threadIdx.x; i < 64 * 64; i += 256) {
    int o = i >> 6, f = i & 63;
    wlT[f * 65 + o] = wl[i];
  }
  if (threadIdx.x < 64) {
    int c = threadIdx.x;
    double mu  = stg[c] / 131072.0;
    double var = stg[64 + c] / 131072.0 - mu * mu;
    double s   = (double)gg[c] / sqrt(var + EPSI);
    scg[c] = (float)s;
    shg[c] = (float)((double)bg[c] - mu * s);
  }
  __syncthreads();
  int lane = threadIdx.x & 63, wid = threadIdx.x >> 6;
  int g = lane >> 4, cc = lane & 15;
  float blv = blp[lane];
  double s1 = 0.0, s2 = 0.0;
  for (int p = 0; p < 4; ++p) {
    int pt = (blockIdx.x * 4 + wid) * 4 + p;
    int b = pt >> 11, n = pt & 2047;
    int ch = n >> 5;                             // gathered CHANNEL is n>>5 (torch-view scramble)
    int r0 = (n & 31) << 6;
    const float* xrow = hpre + (b * CR + ch) * NPT;
    const int* ib = idx16 + ((b * NPT + r0) << 4);
    float sgc = scg[ch], shc = shg[ch];
    float msum = 0.f;
#pragma unroll
    for (int kk = 0; kk < 16; ++kk) {
      int sidx = ib[(((kk << 2) + g) << 4) | cc];
      msum += fmaxf(fmaf(xrow[sidx], sgc, shc), 0.f);    // BN_g inline
    }
    float mval = msum * 0.0625f;
    float xraw = hpre[(b * CR + lane) * NPT + n];
    float xv = fmaxf(fmaf(xraw, scg[lane], shg[lane]), 0.f);
    vstage[wid][lane] = xv - mval;
    float acc = blv;
    for (int f = 0; f < 64; ++f)
      acc += wlT[f * 65 + lane] * vstage[wid][f];
    tpre[(b * CR + lane) * NPT + n] = acc;
    s1 += (double)acc;
    s2 += (double)acc * (double)acc;
  }
  dred[wid][lane][0] = s1; dred[wid][lane][1] = s2;
  __syncthreads();
  if (threadIdx.x < 64) {
    double S1 = dred[0][threadIdx.x][0] + dred[1][threadIdx.x][0] + dred[2][threadIdx.x][0] + dred[3][threadIdx.x][0];
    double S2 = dred[0][threadIdx.x][1] + dred[1][threadIdx.x][1] + dred[2][threadIdx.x][1] + dred[3][threadIdx.x][1];
    atomicAdd(&stats[threadIdx.x], S1);
    atomicAdd(&stats[64 + threadIdx.x], S2);
  }
}

// ===================== conv2_fused (r12..r15-proven): x3 = relu(bn_g(h)) + relu(bn_l(t)) inline; 64->128 conv =====================
__global__ void __launch_bounds__(256) conv2_fused(const float* __restrict__ hpre,
                                                   const float* __restrict__ tpre,
                                                   const double* __restrict__ stg,
                                                   const float* __restrict__ gg,
                                                   const float* __restrict__ bg,
                                                   const double* __restrict__ stl,
                                                   const float* __restrict__ gl,
                                                   const float* __restrict__ bel,
                                                   const float* __restrict__ w,
                                                   const float* __restrict__ bias,
                                                   float* __restrict__ outp,
                                                   double* __restrict__ stats) {
  __shared__ float scg[64], shg[64], scl[64], shl[64];
  __shared__ double red[4][8][2];
  if (threadIdx.x < 64) {
    int c = threadIdx.x;
    double mu  = stg[c] / 131072.0;
    double var = stg[64 + c] / 131072.0 - mu * mu;
    double s   = (double)gg[c] / sqrt(var + EPSI);
    scg[c] = (float)s; shg[c] = (float)((double)bg[c] - mu * s);
    double mu2  = stl[c] / 16384.0;
    double var2 = stl[64 + c] / 16384.0 - mu2 * mu2;
    double s2   = (double)gl[c] / sqrt(var2 + EPSI);
    scl[c] = (float)s2; shl[c] = (float)((double)bel[c] - mu2 * s2);
  }
  __syncthreads();
  int bz = blockIdx.x;                           // 1024 blocks
  int n  = ((bz & 7) << 8) | threadIdx.x;
  int o0 = ((bz >> 3) % 16) * 8;
  int b  = bz / 128;
  const float* hb = hpre + b * CR * NPT + n;
  const float* tb = tpre + b * CR * NPT + n;
  float a[8];
#pragma unroll
  for (int t = 0; t < 8; ++t) a[t] = bias[o0 + t];
  const float* wb = w + o0 * CR;
#pragma unroll 4
  for (int f = 0; f < CR; ++f) {
    float hv = hb[f * NPT], tv = tb[f * NPT];
    float v = fmaxf(fmaf(hv, scg[f], shg[f]), 0.f) + fmaxf(fmaf(tv, scl[f], shl[f]), 0.f);
#pragma unroll
    for (int t = 0; t < 8; ++t) a[t] += wb[t * CR + f] * v;
  }
  float* ob = outp + b * NF * NPT + n;
#pragma unroll
  for (int t = 0; t < 8; ++t) ob[(o0 + t) * NPT] = a[t];
  int lane = threadIdx.x & 63, wid = threadIdx.x >> 6;
#pragma unroll
  for (int j = 0; j < 8; ++j) {
    double s1 = (double)a[j];
    double s2 = (double)a[j] * (double)a[j];
#pragma unroll
    for (int off = 32; off; off >>= 1) { s1 += __shfl_down(s1, off); s2 += __shfl_down(s2, off); }
    if (lane == 0) { red[wid][j][0] = s1; red[wid][j][1] = s2; }
  }
  __syncthreads();
  if (threadIdx.x < 8) {
    int j = threadIdx.x;
    double S1 = red[0][j][0] + red[1][j][0] + red[2][j][0] + red[3][j][0];
    double S2 = red[0][j][1] + red[1][j][1] + red[2][j][1] + red[3][j][1];
    atomicAdd(&stats[o0 + j], S1);
    atomicAdd(&stats[NF + o0 + j], S2);
  }
}

// ===================== conv3_fused (r14/r15-proven): y2 = relu(bn2(y2pre)) + feat inline; 128->256 conv + st3 =====================
__global__ void __launch_bounds__(256) conv3_fused(const float* __restrict__ y2pre,
                                                   const float* __restrict__ feat,
                                                   const double* __restrict__ st2,
                                                   const float* __restrict__ g2,
                                                   const float* __restrict__ be2,
                                                   const float* __restrict__ w,
                                                   const float* __restrict__ bias,
                                                   float* __restrict__ outp,
                                                   double* __restrict__ stats) {
  __shared__ float sc[128], sh[128];
  __shared__ double red[4][8][2];
  for (int c = threadIdx.x; c < 128; c += 256) {
    double mu  = st2[c] / 16384.0;
    double var = st2[128 + c] / 16384.0 - mu * mu;
    double s   = (double)g2[c] / sqrt(var + EPSI);
    sc[c] = (float)s;
    sh[c] = (float)((double)be2[c] - mu * s);
  }
  __syncthreads();
  int bz = blockIdx.x;                           // 2048 blocks: [b(8)][og(32)][ng(8)]
  int n  = ((bz & 7) << 8) | threadIdx.x;
  int o0 = ((bz >> 3) % 32) * 8;
  int b  = bz / 256;
  const float* yb = y2pre + b * NF * NPT + n;
  const float* fb = feat  + b * NF * NPT + n;
  float a[8];
#pragma unroll
  for (int t = 0; t < 8; ++t) a[t] = bias[o0 + t];
  const float* wb = w + o0 * NF;
#pragma unroll 4
  for (int f = 0; f < NF; ++f) {
    float v = fmaxf(fmaf(yb[f * NPT], sc[f], sh[f]), 0.f) + fb[f * NPT];  // bn2+relu+feat inline
#pragma unroll
    for (int t = 0; t < 8; ++t) a[t] += wb[t * NF + f] * v;
  }
  float* ob = outp + b * 2 * NF * NPT + n;
#pragma unroll
  for (int t = 0; t < 8; ++t) ob[(o0 + t) * NPT] = a[t];
  int lane = threadIdx.x & 63, wid = threadIdx.x >> 6;
#pragma unroll
  for (int j = 0; j < 8; ++j) {
    double s1 = (double)a[j];
    double s2 = (double)a[j] * (double)a[j];
#pragma unroll
    for (int off = 32; off; off >>= 1) { s1 += __shfl_down(s1, off); s2 += __shfl_down(s2, off); }
    if (lane == 0) { red[wid][j][0] = s1; red[wid][j][1] = s2; }
  }
  __syncthreads();
  if (threadIdx.x < 8) {
    int j = threadIdx.x;
    double S1 = red[0][j][0] + red[1][j][0] + red[2][j][0] + red[3][j][0];
    double S2 = red[0][j][1] + red[1][j][1] + red[2][j][1] + red[3][j][1];
    atomicAdd(&stats[o0 + j], S1);
    atomicAdd(&stats[256 + o0 + j], S2);
  }
}

// ============================ launch (9 nodes) ============================
extern "C" void kernel_launch(void* const* d_in, const int* in_sizes, int n_in,
                              void* d_out, int out_size, void* d_ws, size_t ws_size,
                              hipStream_t stream) {
  const float* xyz  = (const float*)d_in[0];
  const float* feat = (const float*)d_in[1];
  const float* w1   = (const float*)d_in[2];
  const float* b1   = (const float*)d_in[3];
  const float* g1   = (const float*)d_in[4];
  const float* be1  = (const float*)d_in[5];
  const float* wf   = (const float*)d_in[6];
  const float* bf   = (const float*)d_in[7];
  const float* gg   = (const float*)d_in[8];
  const float* bg   = (const float*)d_in[9];
  const float* wl   = (const float*)d_in[10];
  const float* bl   = (const float*)d_in[11];
  const float* gl   = (const float*)d_in[12];
  const float* bel  = (const float*)d_in[13];
  const float* w2   = (const float*)d_in[14];
  const float* b2   = (const float*)d_in[15];
  const float* g2   = (const float*)d_in[16];
  const float* be2  = (const float*)d_in[17];
  const float* w3   = (const float*)d_in[18];
  const float* b3   = (const float*)d_in[19];
  const float* g3   = (const float*)d_in[20];
  const float* be3  = (const float*)d_in[21];
  float* out = (float*)d_out;

  // d_out scratch (all dead before conv3 writes out):
  float* x1pre = out;                      // 4MB  (pre-BN conv1 out; consumed by zconv)
  float* tpre  = out + 1048576;            // 4MB
  int*  idx16  = (int*)(out + 2097152);    // 1MB
  float* zT    = out + 2359296;            // 4MB  zT[b][n][64]
  // ws: hpre, y2pre, stats (12MB + 9KB footprint, as all passing rounds)
  float*  hpre  = (float*)d_ws;            // 4MB
  float*  y2pre = hpre + 1048576;          // 8MB (pre-BN conv2 out; bn2 applied inside conv3)
  double* stats = (double*)((char*)d_ws + (12u << 20));
  double* st0 = stats;        // 128
  double* stg = stats + 128;  // 128
  double* stl = stats + 256;  // 128
  double* st2 = stats + 384;  // 256
  double* st3 = stats + 640;  // 512

  hipMemsetAsync(stats, 0, 1152 * sizeof(double), stream);

  // 1: kNN (512-thread blocks, 8 queries/block)
  knn_kernel<<<2048, 512, 0, stream>>>(xyz, idx16);
  // 2: conv1 -> x1pre + st0
  conv_stats<128, 64><<<512, 256, 0, stream>>>(feat, w1, b1, x1pre, st0);
  // 3: zconv (bn1 inline) -> zT
  zconv_kernel<<<512, 256, 0, stream>>>(x1pre, st0, g1, be1, wf, bf, zT);
  // 4: gathermax -> hpre (pre-BN max) + stg
  gathermax_kernel<<<1024, 256, 0, stream>>>(zT, idx16, hpre, stg);
  // 5: lap (BN_g inline) -> tpre + stl
  lap_fused<<<1024, 256, 0, stream>>>(hpre, idx16, wl, bl, tpre, stl, stg, gg, bg);
  // 6: conv2 (x3 inline from hpre,tpre) -> y2pre + st2
  conv2_fused<<<1024, 256, 0, stream>>>(hpre, tpre, stg, gg, bg, stl, gl, bel, w2, b2, y2pre, st2);
  // 7: conv3 (bn2 + feat residual inline) -> out + st3
  conv3_fused<<<2048, 256, 0, stream>>>(y2pre, feat, st2, g2, be2, w3, b3, out, st3);
  // 8: bn3 -> out in place
  bn_apply<256><<<1024, 256, 0, stream>>>(out, nullptr, out, st3, g3, be3, 1.0 / 16384.0);
}